// Round 4
// baseline (184.381 us; speedup 1.0000x reference)
//
#include <hip/hip_runtime.h>
#include <hip/hip_bf16.h>

#define BB 8
#define CIN 512
#define COUT 512
#define HH 64
#define WW 64

#define AFF_SCALE 0.044194173824159216f     // 1/sqrt(512)
#define CONV_SCALE 0.014731391274719736f    // 1/sqrt(4608)
#define CONV_SCALE2 (1.0f/4608.0f)

typedef short s16x8 __attribute__((ext_vector_type(8)));
typedef float f32x4 __attribute__((ext_vector_type(4)));

__device__ __forceinline__ unsigned short f2bf(float f) {
  __hip_bfloat16 h = __float2bfloat16(f);
  return *reinterpret_cast<unsigned short*>(&h);
}

// ---------------------------------------------------------------------------
// smod[b*CIN+ic] = dot(style[b,:], w_affine[ic,:]) * AFF_SCALE + ba[ic]
// ---------------------------------------------------------------------------
__global__ __launch_bounds__(256) void affine_kernel(
    const float* __restrict__ style, const float* __restrict__ wa,
    const float* __restrict__ ba, float* __restrict__ smod) {
  int wid  = (blockIdx.x << 2) + (threadIdx.x >> 6);
  int lane = threadIdx.x & 63;
  int b  = wid >> 9;
  int ic = wid & 511;
  const float* s = style + b * CIN;
  const float* w = wa + (size_t)ic * CIN;
  float sum = 0.f;
#pragma unroll
  for (int k = 0; k < CIN / 64; ++k) sum += s[lane + 64 * k] * w[lane + 64 * k];
#pragma unroll
  for (int off = 32; off; off >>= 1) sum += __shfl_down(sum, off, 64);
  if (lane == 0) smod[wid] = sum * AFF_SCALE + ba[ic];
}

// ---------------------------------------------------------------------------
// wsq[oc*CIN+ic] = sum_k w_conv[oc,ic,k]^2
// ---------------------------------------------------------------------------
__global__ __launch_bounds__(256) void wsq_kernel(
    const float* __restrict__ wc, float* __restrict__ wsq) {
  int i = blockIdx.x * 256 + threadIdx.x;
  const float* p = wc + (size_t)i * 9;
  float s = 0.f;
#pragma unroll
  for (int k = 0; k < 9; ++k) { float v = p[k]; s += v * v; }
  wsq[i] = s;
}

// ---------------------------------------------------------------------------
// demod[b*COUT+oc] = rsqrt(CS2 * sum_ic smod^2 * wsq + eps) * CS
// ---------------------------------------------------------------------------
__global__ __launch_bounds__(256) void demod_kernel(
    const float* __restrict__ smod, const float* __restrict__ wsq,
    float* __restrict__ demod) {
  int wid  = (blockIdx.x << 2) + (threadIdx.x >> 6);
  int lane = threadIdx.x & 63;
  int b  = wid >> 9;
  int oc = wid & 511;
  const float* s = smod + b * CIN;
  const float* w = wsq + (size_t)oc * CIN;
  float sum = 0.f;
#pragma unroll
  for (int k = 0; k < CIN / 64; ++k) {
    float sv = s[lane + 64 * k];
    sum += sv * sv * w[lane + 64 * k];
  }
#pragma unroll
  for (int off = 32; off; off >>= 1) sum += __shfl_down(sum, off, 64);
  if (lane == 0) demod[wid] = rsqrtf(sum * CONV_SCALE2 + 1e-8f) * CONV_SCALE;
}

// ---------------------------------------------------------------------------
// premod: xt[b][g][y][x][ic32] bf16 = input[b][ic][y][x] * smod[b][ic]
// ---------------------------------------------------------------------------
__global__ __launch_bounds__(256) void premod_kernel(
    const float* __restrict__ xin, const float* __restrict__ smod,
    ushort* __restrict__ xt) {
  int n = blockIdx.x * 256 + threadIdx.x;   // < 2,097,152
  int kg = n & 3;
  int x  = (n >> 2) & 63;
  int y  = (n >> 8) & 63;
  int g  = (n >> 14) & 15;
  int b  = n >> 18;
  int ic0 = g * 32 + kg * 8;
  const float* sp = smod + b * CIN + ic0;
  const float* xp = xin + (((size_t)b * CIN + ic0) * HH + y) * WW + x;
  s16x8 o;
#pragma unroll
  for (int j = 0; j < 8; ++j) {
    float v = xp[(size_t)j * HH * WW] * sp[j];
    o[j] = (short)f2bf(v);
  }
  *(s16x8*)(xt + (size_t)n * 8) = o;
}

// ---------------------------------------------------------------------------
// wpack: wfrag[widx=g*9+tap][ocg][lane][8] bf16, exact A-fragment lane order:
//   element = wc[oc = ocg*16 + (l&15)][ic = g*32 + (l>>4)*8 + j][kh][kw]
// ---------------------------------------------------------------------------
__global__ __launch_bounds__(256) void wpack_kernel(
    const float* __restrict__ wc, ushort* __restrict__ wfrag) {
  int n = blockIdx.x * 256 + threadIdx.x;   // < 294,912
  int l = n & 63;
  int rem = n >> 6;
  int ocg = rem & 31;
  int rem2 = rem >> 5;          // < 144
  int tap = rem2 % 9;
  int g   = rem2 / 9;
  int oc  = ocg * 16 + (l & 15);
  int ic0 = g * 32 + (l >> 4) * 8;
  int kh = tap / 3, kw = tap - kh * 3;
  s16x8 o;
#pragma unroll
  for (int j = 0; j < 8; ++j) {
    float v = wc[((size_t)oc * CIN + ic0 + j) * 9 + kh * 3 + kw];
    o[j] = (short)f2bf(v);
  }
  *(s16x8*)(wfrag + (size_t)n * 8) = o;
}

// ---------------------------------------------------------------------------
// conv_mfma (R4): A (weights) global->VGPR direct, ping-pong wA[2][8], no ws
// LDS at all. Only B (xs) lives in LDS, double-buffered per ic-group g.
// ONE barrier per g (16 total); 9-tap region is barrier-free so the
// scheduler pipelines ds_read/global_load under MFMAs. Weight prefetch for
// kstep k+1 issued one full tap (~1300 cyc) ahead; k=144 prefetch harmlessly
// reads the first bytes of xt (valid, unused).
// ---------------------------------------------------------------------------
#define XS_ROWSZ 4608
#define XS_SIZE  (6 * XS_ROWSZ)    // 27648 B per buffer

__global__ __launch_bounds__(256, 2) void conv_mfma(
    const ushort* __restrict__ xt,     // [8][16][64][64][32] bf16
    const ushort* __restrict__ wfrag,  // [144][32][64][8] bf16
    const float* __restrict__ demod,
    float* __restrict__ out) {
  __shared__ char lds[2 * XS_SIZE];   // 55,296 B -> 2 blocks/CU

  int tid = threadIdx.x;
  int l = tid & 63, w = tid >> 6;
  int bid = blockIdx.x;
  int ocb = bid & 3;
  int b   = (bid >> 2) & 7;
  int yt  = bid >> 5;           // 0..15
  int y0  = yt * 4;

  f32x4 acc[8][4];
#pragma unroll
  for (int i = 0; i < 8; ++i)
#pragma unroll
    for (int j = 0; j < 4; ++j) acc[i][j] = f32x4{0.f, 0.f, 0.f, 0.f};

  // zero halo columns (ct = 0, 65) in BOTH xs buffers, written once
  if (tid < 96) {
    int r    = tid >> 4;          // 0..5
    int kg   = (tid >> 2) & 3;
    int side = (tid >> 1) & 1;
    int buf  = tid & 1;
    int ct   = side ? 65 : 0;
    int off  = buf * XS_SIZE + r * XS_ROWSZ + (ct >> 3) * 512 + kg * 128 + (ct & 7) * 16;
    *(int4*)(lds + off) = int4{0, 0, 0, 0};
  }

  // staging constants: thread -> (x = tid&63, kg = wave)
  int sx = tid & 63;
  int skg = w;
  int sct = sx + 1;
  int xs_woff = (sct >> 3) * 512 + skg * 128 + (sct & 7) * 16;

  // per-lane weight base: frag fm of kstep k at  wlane + k*16384 + fm*512
  const ushort* wlane = wfrag + (size_t)(ocb * 8) * 512 + (size_t)l * 8;

  s16x8 wA[2][8];
#pragma unroll
  for (int fm = 0; fm < 8; ++fm)
    wA[0][fm] = *(const s16x8*)(wlane + fm * 512);   // k = 0

  // stage xs for g = 0
#pragma unroll
  for (int r = 0; r < 6; ++r) {
    int gy = y0 - 1 + r;
    int4 t = {0, 0, 0, 0};
    if (gy >= 0 && gy < HH)
      t = *(const int4*)(xt + ((((size_t)(b * 16 + 0) * 4096) + gy * 64 + sx) * 32 + skg * 8));
    *(int4*)(lds + r * XS_ROWSZ + xs_woff) = t;
  }
  __syncthreads();

  int4 xv[6];
  for (int g2 = 0; g2 < 8; ++g2) {
#pragma unroll
    for (int gg = 0; gg < 2; ++gg) {
      const int g = g2 * 2 + gg;               // g & 1 == gg (compile-time)
      char* xs_r = lds + gg * XS_SIZE;
      char* xs_w = lds + (gg ^ 1) * XS_SIZE;
#pragma unroll
      for (int tap = 0; tap < 9; ++tap) {
        const int kpar = (gg * 9 + tap) & 1;   // parity of k = g*9+tap (compile-time)

        // prefetch weights for kstep k+1 into the other parity slot
        {
          const ushort* wp = wlane + (size_t)(g * 9 + tap + 1) * 16384;
#pragma unroll
          for (int fm = 0; fm < 8; ++fm)
            wA[kpar ^ 1][fm] = *(const s16x8*)(wp + fm * 512);
        }

        // issue next-g xs global loads late (short live range, ~1 tap cover)
        if (tap == 7) {
          int gn = (g < 15) ? g + 1 : 15;      // g=15 reload is harmless dead work
#pragma unroll
          for (int r = 0; r < 6; ++r) {
            int gy = y0 - 1 + r;
            int4 t = {0, 0, 0, 0};
            if (gy >= 0 && gy < HH)
              t = *(const int4*)(xt + ((((size_t)(b * 16 + gn) * 4096) + gy * 64 + sx) * 32 + skg * 8));
            xv[r] = t;
          }
        }

        const int dy = tap / 3 - 1, dx = tap % 3 - 1;
        const int rb = w + 1 + dy;
        s16x8 bfr[4];
#pragma unroll
        for (int fn = 0; fn < 4; ++fn) {
          int c2 = fn * 16 + (l & 15) + dx + 1;   // 0..65
          bfr[fn] = *(const s16x8*)(xs_r + rb * XS_ROWSZ + (c2 >> 3) * 512 + (l >> 4) * 128 + (c2 & 7) * 16);
        }

        __builtin_amdgcn_s_setprio(1);
#pragma unroll
        for (int fm = 0; fm < 8; ++fm) {
#pragma unroll
          for (int fn = 0; fn < 4; ++fn)
            acc[fm][fn] = __builtin_amdgcn_mfma_f32_16x16x32_bf16(wA[kpar][fm], bfr[fn], acc[fm][fn], 0, 0, 0);
        }
        __builtin_amdgcn_s_setprio(0);

        if (tap == 8) {
          // publish next g's xs, then LDS-only drain + barrier
#pragma unroll
          for (int r = 0; r < 6; ++r)
            *(int4*)(xs_w + r * XS_ROWSZ + xs_woff) = xv[r];
          asm volatile("s_waitcnt lgkmcnt(0)" ::: "memory");
          __builtin_amdgcn_sched_barrier(0);
          __builtin_amdgcn_s_barrier();
          __builtin_amdgcn_sched_barrier(0);
        }
      }
    }
  }

  // ---- epilogue: demod scale + store ----
  int oc_base = ocb * 128;
  int gy = y0 + w;
#pragma unroll
  for (int fm = 0; fm < 8; ++fm) {
#pragma unroll
    for (int r = 0; r < 4; ++r) {
      int oc = oc_base + fm * 16 + (l >> 4) * 4 + r;
      float dm = demod[b * COUT + oc];
#pragma unroll
      for (int fn = 0; fn < 4; ++fn) {
        out[(((size_t)b * COUT + oc) * 4096) + gy * 64 + fn * 16 + (l & 15)] =
            acc[fm][fn][r] * dm;
      }
    }
  }
}

// ---------------------------------------------------------------------------
extern "C" void kernel_launch(void* const* d_in, const int* in_sizes, int n_in,
                              void* d_out, int out_size, void* d_ws, size_t ws_size,
                              hipStream_t stream) {
  const float* input = (const float*)d_in[0];  // [8,512,64,64]
  const float* style = (const float*)d_in[1];  // [8,512]
  const float* wa    = (const float*)d_in[2];  // [512,512]
  const float* ba    = (const float*)d_in[3];  // [1,512]
  const float* wconv = (const float*)d_in[4];  // [512,512,3,3]
  float* out = (float*)d_out;

  float* smod  = (float*)d_ws;                    // 4096 f
  float* demod = smod + BB * CIN;                 // 4096 f
  float* wsq   = demod + BB * COUT;               // 262144 f
  ushort* wfrag = (ushort*)(wsq + (size_t)COUT * CIN);   // 2,359,296 us (4.5 MB)
  ushort* xt    = wfrag + (size_t)16 * 9 * 32 * 64 * 8;  // 16,777,216 us (32 MB)

  affine_kernel<<<BB * CIN / 4, 256, 0, stream>>>(style, wa, ba, smod);
  wsq_kernel<<<COUT * CIN / 256, 256, 0, stream>>>(wconv, wsq);
  demod_kernel<<<BB * COUT / 4, 256, 0, stream>>>(smod, wsq, demod);
  wpack_kernel<<<16 * 9 * 32 * 64 / 256, 256, 0, stream>>>(wconv, wfrag);
  premod_kernel<<<BB * 16 * 64 * 64 * 4 / 256, 256, 0, stream>>>(input, smod, xt);
  conv_mfma<<<BB * 4 * 16, 256, 0, stream>>>(xt, wfrag, demod, out);
}

// Round 5
// 169.102 us; speedup vs baseline: 1.0904x; 1.0904x over previous
//
#include <hip/hip_runtime.h>
#include <hip/hip_bf16.h>

#define BB 8
#define CIN 512
#define COUT 512
#define HH 64
#define WW 64

#define AFF_SCALE 0.044194173824159216f     // 1/sqrt(512)
#define CONV_SCALE 0.014731391274719736f    // 1/sqrt(4608)
#define CONV_SCALE2 (1.0f/4608.0f)

typedef short s16x8 __attribute__((ext_vector_type(8)));
typedef float f32x4 __attribute__((ext_vector_type(4)));

__device__ __forceinline__ unsigned short f2bf(float f) {
  __hip_bfloat16 h = __float2bfloat16(f);
  return *reinterpret_cast<unsigned short*>(&h);
}

// zero-register global->LDS DMA, 16B per lane; LDS dest = uniform base + lane*16
__device__ __forceinline__ void gload_lds16(const void* g, void* l) {
  __builtin_amdgcn_global_load_lds(
      (const __attribute__((address_space(1))) unsigned int*)g,
      (__attribute__((address_space(3))) unsigned int*)l, 16, 0, 0);
}

// ---------------------------------------------------------------------------
// smod[b*CIN+ic] = dot(style[b,:], w_affine[ic,:]) * AFF_SCALE + ba[ic]
// ---------------------------------------------------------------------------
__global__ __launch_bounds__(256) void affine_kernel(
    const float* __restrict__ style, const float* __restrict__ wa,
    const float* __restrict__ ba, float* __restrict__ smod) {
  int wid  = (blockIdx.x << 2) + (threadIdx.x >> 6);
  int lane = threadIdx.x & 63;
  int b  = wid >> 9;
  int ic = wid & 511;
  const float* s = style + b * CIN;
  const float* w = wa + (size_t)ic * CIN;
  float sum = 0.f;
#pragma unroll
  for (int k = 0; k < CIN / 64; ++k) sum += s[lane + 64 * k] * w[lane + 64 * k];
#pragma unroll
  for (int off = 32; off; off >>= 1) sum += __shfl_down(sum, off, 64);
  if (lane == 0) smod[wid] = sum * AFF_SCALE + ba[ic];
}

// ---------------------------------------------------------------------------
// wsq[oc*CIN+ic] = sum_k w_conv[oc,ic,k]^2
// ---------------------------------------------------------------------------
__global__ __launch_bounds__(256) void wsq_kernel(
    const float* __restrict__ wc, float* __restrict__ wsq) {
  int i = blockIdx.x * 256 + threadIdx.x;
  const float* p = wc + (size_t)i * 9;
  float s = 0.f;
#pragma unroll
  for (int k = 0; k < 9; ++k) { float v = p[k]; s += v * v; }
  wsq[i] = s;
}

// ---------------------------------------------------------------------------
// demod[b*COUT+oc] = rsqrt(CS2 * sum_ic smod^2 * wsq + eps) * CS
// ---------------------------------------------------------------------------
__global__ __launch_bounds__(256) void demod_kernel(
    const float* __restrict__ smod, const float* __restrict__ wsq,
    float* __restrict__ demod) {
  int wid  = (blockIdx.x << 2) + (threadIdx.x >> 6);
  int lane = threadIdx.x & 63;
  int b  = wid >> 9;
  int oc = wid & 511;
  const float* s = smod + b * CIN;
  const float* w = wsq + (size_t)oc * CIN;
  float sum = 0.f;
#pragma unroll
  for (int k = 0; k < CIN / 64; ++k) {
    float sv = s[lane + 64 * k];
    sum += sv * sv * w[lane + 64 * k];
  }
#pragma unroll
  for (int off = 32; off; off >>= 1) sum += __shfl_down(sum, off, 64);
  if (lane == 0) demod[wid] = rsqrtf(sum * CONV_SCALE2 + 1e-8f) * CONV_SCALE;
}

// ---------------------------------------------------------------------------
// premod: xt[b][g][y][x][ic32] bf16 = input[b][ic][y][x] * smod[b][ic]
// ---------------------------------------------------------------------------
__global__ __launch_bounds__(256) void premod_kernel(
    const float* __restrict__ xin, const float* __restrict__ smod,
    ushort* __restrict__ xt) {
  int n = blockIdx.x * 256 + threadIdx.x;   // < 2,097,152
  int kg = n & 3;
  int x  = (n >> 2) & 63;
  int y  = (n >> 8) & 63;
  int g  = (n >> 14) & 15;
  int b  = n >> 18;
  int ic0 = g * 32 + kg * 8;
  const float* sp = smod + b * CIN + ic0;
  const float* xp = xin + (((size_t)b * CIN + ic0) * HH + y) * WW + x;
  s16x8 o;
#pragma unroll
  for (int j = 0; j < 8; ++j) {
    float v = xp[(size_t)j * HH * WW] * sp[j];
    o[j] = (short)f2bf(v);
  }
  *(s16x8*)(xt + (size_t)n * 8) = o;
}

// ---------------------------------------------------------------------------
// wpack: wfrag[widx=g*9+tap][ocg][lane][8] bf16, exact A-fragment lane order:
//   element = wc[oc = ocg*16 + (l&15)][ic = g*32 + (l>>4)*8 + j][kh][kw]
// ---------------------------------------------------------------------------
__global__ __launch_bounds__(256) void wpack_kernel(
    const float* __restrict__ wc, ushort* __restrict__ wfrag) {
  int n = blockIdx.x * 256 + threadIdx.x;   // < 294,912
  int l = n & 63;
  int rem = n >> 6;
  int ocg = rem & 31;
  int rem2 = rem >> 5;          // < 144
  int tap = rem2 % 9;
  int g   = rem2 / 9;
  int oc  = ocg * 16 + (l & 15);
  int ic0 = g * 32 + (l >> 4) * 8;
  int kh = tap / 3, kw = tap - kh * 3;
  s16x8 o;
#pragma unroll
  for (int j = 0; j < 8; ++j) {
    float v = wc[((size_t)oc * CIN + ic0 + j) * 9 + kh * 3 + kw];
    o[j] = (short)f2bf(v);
  }
  *(s16x8*)(wfrag + (size_t)n * 8) = o;
}

// ---------------------------------------------------------------------------
// conv_mfma (R5): A weights global->VGPR ping-pong (as R4), but xs staging
// via zero-register global_load_lds DMA into a LINEAR [row][col0..65][kg]
// layout (halo cols always-zero, zeroed once). Bank-conflict-free B reads via
// both-sides XOR swizzle: kg ^= (col>>1)&3, applied to the per-lane GLOBAL
// source at staging and to the precomputed read offsets. One barrier per
// ic-group g (16 total) with conservative vmcnt(0); staging issued at tap 6
// for ~2.5 taps of latency cover. Register budget ~110 VGPR (no spill).
// ---------------------------------------------------------------------------
#define XS_ROW 4224                 // 66 cols * 4 kg * 16 B
#define XS_BUF (6 * XS_ROW)         // 25344 B per buffer

__global__ __launch_bounds__(256, 2) void conv_mfma(
    const ushort* __restrict__ xt,     // [8][16][64][64][32] bf16
    const ushort* __restrict__ wfrag,  // [144][32][64][8] bf16
    const float* __restrict__ demod,
    float* __restrict__ out) {
  __shared__ char lds[2 * XS_BUF];    // 50688 B -> 2 blocks/CU

  int tid = threadIdx.x;
  int l = tid & 63, w = tid >> 6;
  int bid = blockIdx.x;
  int ocb = bid & 3;
  int b   = (bid >> 2) & 7;
  int yt  = bid >> 5;           // 0..15
  int y0  = yt * 4;

  f32x4 acc[8][4];
#pragma unroll
  for (int i = 0; i < 8; ++i)
#pragma unroll
    for (int j = 0; j < 4; ++j) acc[i][j] = f32x4{0.f, 0.f, 0.f, 0.f};

  // zero always-zero halo COLUMNS (col 0 -> chunks 0..3, col 65 -> 260..263)
  if (tid < 96) {
    int buf = tid & 1, side = (tid >> 1) & 1, kgz = (tid >> 2) & 3, r = tid >> 4;
    int chunk = side ? (260 + kgz) : kgz;
    *(int4*)(lds + buf * XS_BUF + r * XS_ROW + chunk * 16) = int4{0, 0, 0, 0};
  }
  // zero y-halo ROWS for edge blocks (never re-staged -> stay zero)
  if (y0 == 0) {
    for (int i = tid; i < 512; i += 256) {
      int buf = i & 1, chunk = 4 + (i >> 1);
      *(int4*)(lds + buf * XS_BUF + chunk * 16) = int4{0, 0, 0, 0};
    }
  }
  if (y0 == 60) {
    for (int i = tid; i < 512; i += 256) {
      int buf = i & 1, chunk = 4 + (i >> 1);
      *(int4*)(lds + buf * XS_BUF + 5 * XS_ROW + chunk * 16) = int4{0, 0, 0, 0};
    }
  }

  // precomputed B-fragment read offsets (swizzled), static-indexed in loop
  int lm = l & 15, kg = l >> 4;
  int boffs[4][3];
#pragma unroll
  for (int fn = 0; fn < 4; ++fn)
#pragma unroll
    for (int dxi = 0; dxi < 3; ++dxi) {
      int col = fn * 16 + lm + dxi;                       // 0..65
      boffs[fn][dxi] = (col * 4 + (kg ^ ((col >> 1) & 3))) * 16;
    }

  // staging: wave w covers quarter q=w of each row; per-lane PRE-SWIZZLED
  // global source offset within a 4KB xt row
  int col_s = 1 + w * 16 + (l >> 2);
  int srcoff = (col_s - 1) * 64 + ((l & 3) ^ ((col_s >> 1) & 3)) * 16;
  int lds_woff = 64 + w * 1024;   // + r*XS_ROW (+buf*XS_BUF)

  const char* xtb = (const char*)xt;
  const char* wl = (const char*)wfrag + (size_t)(ocb * 8) * 1024 + (size_t)l * 16;

  s16x8 wA[2][8];
#pragma unroll
  for (int fm = 0; fm < 8; ++fm)
    wA[0][fm] = *(const s16x8*)(wl + fm * 1024);          // kstep 0

  // prologue: stage g=0 into buffer 0
  {
    size_t gbase = (size_t)(b * 16) * 262144;             // (b,g) plane, bytes
#pragma unroll
    for (int r = 0; r < 6; ++r) {
      int gy = y0 - 1 + r;
      if (gy >= 0 && gy < HH)
        gload_lds16(xtb + gbase + (size_t)gy * 4096 + srcoff,
                    lds + r * XS_ROW + lds_woff);
    }
  }
  __syncthreads();

  for (int g2 = 0; g2 < 8; ++g2) {
#pragma unroll
    for (int gg = 0; gg < 2; ++gg) {
      const int g = g2 * 2 + gg;
      char* xs_r = lds + gg * XS_BUF;
      char* xs_w = lds + (gg ^ 1) * XS_BUF;
#pragma unroll
      for (int tap = 0; tap < 9; ++tap) {
        const int kpar = (gg * 9 + tap) & 1;

        // stage next g's xs early (tap 6) -> ~2.5 taps of latency cover
        if (tap == 6 && g < 15) {
          __builtin_amdgcn_sched_barrier(0);
          size_t gbase = (size_t)(b * 16 + g + 1) * 262144;
#pragma unroll
          for (int r = 0; r < 6; ++r) {
            int gy = y0 - 1 + r;
            if (gy >= 0 && gy < HH)
              gload_lds16(xtb + gbase + (size_t)gy * 4096 + srcoff,
                          xs_w + r * XS_ROW + lds_woff);
          }
          __builtin_amdgcn_sched_barrier(0);
        }

        // prefetch weights for kstep k+1 into other parity slot
        if (tap < 8 || g < 15) {
          const char* wp = wl + (size_t)(g * 9 + tap + 1) * 32768;
#pragma unroll
          for (int fm = 0; fm < 8; ++fm)
            wA[kpar ^ 1][fm] = *(const s16x8*)(wp + fm * 1024);
        }

        const int dy = tap / 3 - 1, dxi = tap % 3;
        const int rb = w + 1 + dy;
        s16x8 bfr[4];
#pragma unroll
        for (int fn = 0; fn < 4; ++fn)
          bfr[fn] = *(const s16x8*)(xs_r + rb * XS_ROW + boffs[fn][dxi]);

        __builtin_amdgcn_s_setprio(1);
#pragma unroll
        for (int fm = 0; fm < 8; ++fm) {
#pragma unroll
          for (int fn = 0; fn < 4; ++fn)
            acc[fm][fn] = __builtin_amdgcn_mfma_f32_16x16x32_bf16(wA[kpar][fm], bfr[fn], acc[fm][fn], 0, 0, 0);
        }
        __builtin_amdgcn_s_setprio(0);

        if (tap == 8 && g < 15) {
          // conservative full drain once per g: staging (issued tap 6) +
          // weight prefetch complete before buffer swap
          __builtin_amdgcn_sched_barrier(0);
          asm volatile("s_waitcnt vmcnt(0) lgkmcnt(0)" ::: "memory");
          __builtin_amdgcn_sched_barrier(0);
          __builtin_amdgcn_s_barrier();
          __builtin_amdgcn_sched_barrier(0);
        }
      }
    }
  }

  // ---- epilogue: demod scale + store ----
  int oc_base = ocb * 128;
  int gy = y0 + w;
#pragma unroll
  for (int fm = 0; fm < 8; ++fm) {
#pragma unroll
    for (int r = 0; r < 4; ++r) {
      int oc = oc_base + fm * 16 + (l >> 4) * 4 + r;
      float dm = demod[b * COUT + oc];
#pragma unroll
      for (int fn = 0; fn < 4; ++fn) {
        out[(((size_t)b * COUT + oc) * 4096) + gy * 64 + fn * 16 + (l & 15)] =
            acc[fm][fn][r] * dm;
      }
    }
  }
}

// ---------------------------------------------------------------------------
extern "C" void kernel_launch(void* const* d_in, const int* in_sizes, int n_in,
                              void* d_out, int out_size, void* d_ws, size_t ws_size,
                              hipStream_t stream) {
  const float* input = (const float*)d_in[0];  // [8,512,64,64]
  const float* style = (const float*)d_in[1];  // [8,512]
  const float* wa    = (const float*)d_in[2];  // [512,512]
  const float* ba    = (const float*)d_in[3];  // [1,512]
  const float* wconv = (const float*)d_in[4];  // [512,512,3,3]
  float* out = (float*)d_out;

  float* smod  = (float*)d_ws;                    // 4096 f
  float* demod = smod + BB * CIN;                 // 4096 f
  float* wsq   = demod + BB * COUT;               // 262144 f
  ushort* wfrag = (ushort*)(wsq + (size_t)COUT * CIN);   // 2,359,296 us (4.5 MB)
  ushort* xt    = wfrag + (size_t)16 * 9 * 32 * 64 * 8;  // 16,777,216 us (32 MB)

  affine_kernel<<<BB * CIN / 4, 256, 0, stream>>>(style, wa, ba, smod);
  wsq_kernel<<<COUT * CIN / 256, 256, 0, stream>>>(wconv, wsq);
  demod_kernel<<<BB * COUT / 4, 256, 0, stream>>>(smod, wsq, demod);
  wpack_kernel<<<16 * 9 * 32 * 64 / 256, 256, 0, stream>>>(wconv, wfrag);
  premod_kernel<<<BB * 16 * 64 * 64 * 4 / 256, 256, 0, stream>>>(input, smod, xt);
  conv_mfma<<<BB * 4 * 16, 256, 0, stream>>>(xt, wfrag, demod, out);
}

// Round 6
// 160.812 us; speedup vs baseline: 1.1466x; 1.0516x over previous
//
#include <hip/hip_runtime.h>
#include <hip/hip_bf16.h>

#define BB 8
#define CIN 512
#define COUT 512
#define HH 64
#define WW 64

#define AFF_SCALE 0.044194173824159216f     // 1/sqrt(512)
#define CONV_SCALE 0.014731391274719736f    // 1/sqrt(4608)
#define CONV_SCALE2 (1.0f/4608.0f)

typedef short s16x8 __attribute__((ext_vector_type(8)));
typedef float f32x4 __attribute__((ext_vector_type(4)));

__device__ __forceinline__ unsigned short f2bf(float f) {
  __hip_bfloat16 h = __float2bfloat16(f);
  return *reinterpret_cast<unsigned short*>(&h);
}

// zero-register global->LDS DMA, 16B per lane; LDS dest = uniform base + lane*16
__device__ __forceinline__ void gload_lds16(const void* g, void* l) {
  __builtin_amdgcn_global_load_lds(
      (const __attribute__((address_space(1))) unsigned int*)g,
      (__attribute__((address_space(3))) unsigned int*)l, 16, 0, 0);
}

// ---------------------------------------------------------------------------
// smod[b*CIN+ic] = dot(style[b,:], w_affine[ic,:]) * AFF_SCALE + ba[ic]
// ---------------------------------------------------------------------------
__global__ __launch_bounds__(256) void affine_kernel(
    const float* __restrict__ style, const float* __restrict__ wa,
    const float* __restrict__ ba, float* __restrict__ smod) {
  int wid  = (blockIdx.x << 2) + (threadIdx.x >> 6);
  int lane = threadIdx.x & 63;
  int b  = wid >> 9;
  int ic = wid & 511;
  const float* s = style + b * CIN;
  const float* w = wa + (size_t)ic * CIN;
  float sum = 0.f;
#pragma unroll
  for (int k = 0; k < CIN / 64; ++k) sum += s[lane + 64 * k] * w[lane + 64 * k];
#pragma unroll
  for (int off = 32; off; off >>= 1) sum += __shfl_down(sum, off, 64);
  if (lane == 0) smod[wid] = sum * AFF_SCALE + ba[ic];
}

// ---------------------------------------------------------------------------
// wsq[oc*CIN+ic] = sum_k w_conv[oc,ic,k]^2
// ---------------------------------------------------------------------------
__global__ __launch_bounds__(256) void wsq_kernel(
    const float* __restrict__ wc, float* __restrict__ wsq) {
  int i = blockIdx.x * 256 + threadIdx.x;
  const float* p = wc + (size_t)i * 9;
  float s = 0.f;
#pragma unroll
  for (int k = 0; k < 9; ++k) { float v = p[k]; s += v * v; }
  wsq[i] = s;
}

// ---------------------------------------------------------------------------
// demod[b*COUT+oc] = rsqrt(CS2 * sum_ic smod^2 * wsq + eps) * CS
// ---------------------------------------------------------------------------
__global__ __launch_bounds__(256) void demod_kernel(
    const float* __restrict__ smod, const float* __restrict__ wsq,
    float* __restrict__ demod) {
  int wid  = (blockIdx.x << 2) + (threadIdx.x >> 6);
  int lane = threadIdx.x & 63;
  int b  = wid >> 9;
  int oc = wid & 511;
  const float* s = smod + b * CIN;
  const float* w = wsq + (size_t)oc * CIN;
  float sum = 0.f;
#pragma unroll
  for (int k = 0; k < CIN / 64; ++k) {
    float sv = s[lane + 64 * k];
    sum += sv * sv * w[lane + 64 * k];
  }
#pragma unroll
  for (int off = 32; off; off >>= 1) sum += __shfl_down(sum, off, 64);
  if (lane == 0) demod[wid] = rsqrtf(sum * CONV_SCALE2 + 1e-8f) * CONV_SCALE;
}

// ---------------------------------------------------------------------------
// premod: xt[b][g][y][x][ic32] bf16 = input[b][ic][y][x] * smod[b][ic]
// ---------------------------------------------------------------------------
__global__ __launch_bounds__(256) void premod_kernel(
    const float* __restrict__ xin, const float* __restrict__ smod,
    ushort* __restrict__ xt) {
  int n = blockIdx.x * 256 + threadIdx.x;   // < 2,097,152
  int kg = n & 3;
  int x  = (n >> 2) & 63;
  int y  = (n >> 8) & 63;
  int g  = (n >> 14) & 15;
  int b  = n >> 18;
  int ic0 = g * 32 + kg * 8;
  const float* sp = smod + b * CIN + ic0;
  const float* xp = xin + (((size_t)b * CIN + ic0) * HH + y) * WW + x;
  s16x8 o;
#pragma unroll
  for (int j = 0; j < 8; ++j) {
    float v = xp[(size_t)j * HH * WW] * sp[j];
    o[j] = (short)f2bf(v);
  }
  *(s16x8*)(xt + (size_t)n * 8) = o;
}

// ---------------------------------------------------------------------------
// wpack: wfrag[widx=g*9+tap][ocg][lane][8] bf16, exact A-fragment lane order:
//   element = wc[oc = ocg*16 + (l&15)][ic = g*32 + (l>>4)*8 + j][kh][kw]
// ---------------------------------------------------------------------------
__global__ __launch_bounds__(256) void wpack_kernel(
    const float* __restrict__ wc, ushort* __restrict__ wfrag) {
  int n = blockIdx.x * 256 + threadIdx.x;   // < 294,912
  int l = n & 63;
  int rem = n >> 6;
  int ocg = rem & 31;
  int rem2 = rem >> 5;          // < 144
  int tap = rem2 % 9;
  int g   = rem2 / 9;
  int oc  = ocg * 16 + (l & 15);
  int ic0 = g * 32 + (l >> 4) * 8;
  int kh = tap / 3, kw = tap - kh * 3;
  s16x8 o;
#pragma unroll
  for (int j = 0; j < 8; ++j) {
    float v = wc[((size_t)oc * CIN + ic0 + j) * 9 + kh * 3 + kw];
    o[j] = (short)f2bf(v);
  }
  *(s16x8*)(wfrag + (size_t)n * 8) = o;
}

// ---------------------------------------------------------------------------
// conv_mfma (R6): R5 structure (xs via global_load_lds DMA, both-sides XOR
// swizzle, 16 barriers) but weights in a 3-slot HALF-CLUSTER rotation
// wH[3][4] (48 VGPR) instead of the 64-VGPR full-kstep ping-pong that
// spilled in R4/R5. Prefetch distance = 2 half-clusters (~310 cyc > L2
// latency). All slot indices compile-time: 36 phases per g2-iteration,
// 36 % 3 == 0, so the rotation invariant carries across the runtime g2 loop.
// VGPR tally ~96 < 128 -> no spill.
// ---------------------------------------------------------------------------
#define XS_ROW 4224                 // 66 cols * 4 kg * 16 B
#define XS_BUF (6 * XS_ROW)         // 25344 B per buffer

__global__ __launch_bounds__(256, 2) void conv_mfma(
    const ushort* __restrict__ xt,     // [8][16][64][64][32] bf16
    const ushort* __restrict__ wfrag,  // [144][32][64][8] bf16
    const float* __restrict__ demod,
    float* __restrict__ out) {
  __shared__ char lds[2 * XS_BUF];    // 50688 B -> 2 blocks/CU

  int tid = threadIdx.x;
  int l = tid & 63, w = tid >> 6;
  int bid = blockIdx.x;
  int ocb = bid & 3;
  int b   = (bid >> 2) & 7;
  int yt  = bid >> 5;           // 0..15
  int y0  = yt * 4;

  f32x4 acc[8][4];
#pragma unroll
  for (int i = 0; i < 8; ++i)
#pragma unroll
    for (int j = 0; j < 4; ++j) acc[i][j] = f32x4{0.f, 0.f, 0.f, 0.f};

  // zero always-zero halo COLUMNS (col 0 -> chunks 0..3, col 65 -> 260..263)
  if (tid < 96) {
    int buf = tid & 1, side = (tid >> 1) & 1, kgz = (tid >> 2) & 3, r = tid >> 4;
    int chunk = side ? (260 + kgz) : kgz;
    *(int4*)(lds + buf * XS_BUF + r * XS_ROW + chunk * 16) = int4{0, 0, 0, 0};
  }
  // zero y-halo ROWS for edge blocks (never re-staged -> stay zero)
  if (y0 == 0) {
    for (int i = tid; i < 512; i += 256) {
      int buf = i & 1, chunk = 4 + (i >> 1);
      *(int4*)(lds + buf * XS_BUF + chunk * 16) = int4{0, 0, 0, 0};
    }
  }
  if (y0 == 60) {
    for (int i = tid; i < 512; i += 256) {
      int buf = i & 1, chunk = 4 + (i >> 1);
      *(int4*)(lds + buf * XS_BUF + 5 * XS_ROW + chunk * 16) = int4{0, 0, 0, 0};
    }
  }

  // precomputed B-fragment read offsets (swizzled), static-indexed in loop
  int lm = l & 15, kg = l >> 4;
  int boffs[4][3];
#pragma unroll
  for (int fn = 0; fn < 4; ++fn)
#pragma unroll
    for (int dxi = 0; dxi < 3; ++dxi) {
      int col = fn * 16 + lm + dxi;                       // 0..65
      boffs[fn][dxi] = (col * 4 + (kg ^ ((col >> 1) & 3))) * 16;
    }

  // staging: wave w covers quarter q=w of each row; per-lane PRE-SWIZZLED
  // global source offset within a 4KB xt row
  int col_s = 1 + w * 16 + (l >> 2);
  int srcoff = (col_s - 1) * 64 + ((l & 3) ^ ((col_s >> 1) & 3)) * 16;
  int lds_woff = 64 + w * 1024;   // + r*XS_ROW (+buf*XS_BUF)

  const char* xtb = (const char*)xt;
  const char* wl = (const char*)wfrag + (size_t)(ocb * 8) * 1024 + (size_t)l * 16;

  // 3-slot half-cluster rotation: slot s holds half-cluster H with H%3==s.
  // Half H = kstep (H>>1), frags (H&1)*4 .. +3.
  s16x8 wH[3][4];
#pragma unroll
  for (int q = 0; q < 4; ++q) wH[0][q] = *(const s16x8*)(wl + q * 1024);          // H=0
#pragma unroll
  for (int q = 0; q < 4; ++q) wH[1][q] = *(const s16x8*)(wl + 4096 + q * 1024);   // H=1

  // prologue: stage g=0 into buffer 0
  {
    size_t gbase = (size_t)(b * 16) * 262144;             // (b,g) plane, bytes
#pragma unroll
    for (int r = 0; r < 6; ++r) {
      int gy = y0 - 1 + r;
      if (gy >= 0 && gy < HH)
        gload_lds16(xtb + gbase + (size_t)gy * 4096 + srcoff,
                    lds + r * XS_ROW + lds_woff);
    }
  }
  __syncthreads();

  for (int g2 = 0; g2 < 8; ++g2) {
    const char* wg = wl + (size_t)g2 * 589824;   // base of kstep 18*g2
#pragma unroll
    for (int gg = 0; gg < 2; ++gg) {
      char* xs_r = lds + gg * XS_BUF;
      char* xs_w = lds + (gg ^ 1) * XS_BUF;
#pragma unroll
      for (int tap = 0; tap < 9; ++tap) {
        const int X0 = 2 * (gg * 9 + tap);       // even phase id (compile-time)

        // stage next g's xs early (tap 6) -> ~2.5 taps of latency cover
        if (tap == 6 && (gg == 0 || g2 < 7)) {
          __builtin_amdgcn_sched_barrier(0);
          size_t gbase = (size_t)(b * 16 + g2 * 2 + gg + 1) * 262144;
#pragma unroll
          for (int r = 0; r < 6; ++r) {
            int gy = y0 - 1 + r;
            if (gy >= 0 && gy < HH)
              gload_lds16(xtb + gbase + (size_t)gy * 4096 + srcoff,
                          xs_w + r * XS_ROW + lds_woff);
          }
          __builtin_amdgcn_sched_barrier(0);
        }

        // B fragments for this tap
        const int dy = tap / 3 - 1, dxi = tap % 3;
        const int rb = w + 1 + dy;
        s16x8 bfr[4];
#pragma unroll
        for (int fn = 0; fn < 4; ++fn)
          bfr[fn] = *(const s16x8*)(xs_r + rb * XS_ROW + boffs[fn][dxi]);

        // ---- phase h=0: compute frags 0..3, prefetch half X0+2 ----
        {
          const int u = X0 % 3, v = (X0 + 2) % 3;
          const char* wp = wg + (size_t)((X0 + 2) >> 1) * 32768 + ((X0 + 2) & 1) * 4096;
#pragma unroll
          for (int q = 0; q < 4; ++q) wH[v][q] = *(const s16x8*)(wp + q * 1024);
          __builtin_amdgcn_s_setprio(1);
#pragma unroll
          for (int q = 0; q < 4; ++q)
#pragma unroll
            for (int fn = 0; fn < 4; ++fn)
              acc[q][fn] = __builtin_amdgcn_mfma_f32_16x16x32_bf16(wH[u][q], bfr[fn], acc[q][fn], 0, 0, 0);
          __builtin_amdgcn_s_setprio(0);
        }
        // ---- phase h=1: compute frags 4..7, prefetch half X0+3 ----
        {
          const int u = (X0 + 1) % 3, v = (X0 + 3) % 3;
          const char* wp = wg + (size_t)((X0 + 3) >> 1) * 32768 + ((X0 + 3) & 1) * 4096;
#pragma unroll
          for (int q = 0; q < 4; ++q) wH[v][q] = *(const s16x8*)(wp + q * 1024);
          __builtin_amdgcn_s_setprio(1);
#pragma unroll
          for (int q = 0; q < 4; ++q)
#pragma unroll
            for (int fn = 0; fn < 4; ++fn)
              acc[4 + q][fn] = __builtin_amdgcn_mfma_f32_16x16x32_bf16(wH[u][q], bfr[fn], acc[4 + q][fn], 0, 0, 0);
          __builtin_amdgcn_s_setprio(0);
        }

        if (tap == 8 && (gg == 0 || g2 < 7)) {
          // drain staging + weight prefetch before xs buffer swap
          __builtin_amdgcn_sched_barrier(0);
          asm volatile("s_waitcnt vmcnt(0) lgkmcnt(0)" ::: "memory");
          __builtin_amdgcn_sched_barrier(0);
          __builtin_amdgcn_s_barrier();
          __builtin_amdgcn_sched_barrier(0);
        }
      }
    }
  }

  // ---- epilogue: demod scale + store ----
  int oc_base = ocb * 128;
  int gy = y0 + w;
#pragma unroll
  for (int fm = 0; fm < 8; ++fm) {
#pragma unroll
    for (int r = 0; r < 4; ++r) {
      int oc = oc_base + fm * 16 + (l >> 4) * 4 + r;
      float dm = demod[b * COUT + oc];
#pragma unroll
      for (int fn = 0; fn < 4; ++fn) {
        out[(((size_t)b * COUT + oc) * 4096) + gy * 64 + fn * 16 + (l & 15)] =
            acc[fm][fn][r] * dm;
      }
    }
  }
}

// ---------------------------------------------------------------------------
extern "C" void kernel_launch(void* const* d_in, const int* in_sizes, int n_in,
                              void* d_out, int out_size, void* d_ws, size_t ws_size,
                              hipStream_t stream) {
  const float* input = (const float*)d_in[0];  // [8,512,64,64]
  const float* style = (const float*)d_in[1];  // [8,512]
  const float* wa    = (const float*)d_in[2];  // [512,512]
  const float* ba    = (const float*)d_in[3];  // [1,512]
  const float* wconv = (const float*)d_in[4];  // [512,512,3,3]
  float* out = (float*)d_out;

  float* smod  = (float*)d_ws;                    // 4096 f
  float* demod = smod + BB * CIN;                 // 4096 f
  float* wsq   = demod + BB * COUT;               // 262144 f
  ushort* wfrag = (ushort*)(wsq + (size_t)COUT * CIN);   // 2,359,296 us (4.5 MB)
  ushort* xt    = wfrag + (size_t)16 * 9 * 32 * 64 * 8;  // 16,777,216 us (32 MB)

  affine_kernel<<<BB * CIN / 4, 256, 0, stream>>>(style, wa, ba, smod);
  wsq_kernel<<<COUT * CIN / 256, 256, 0, stream>>>(wconv, wsq);
  demod_kernel<<<BB * COUT / 4, 256, 0, stream>>>(smod, wsq, demod);
  wpack_kernel<<<16 * 9 * 32 * 64 / 256, 256, 0, stream>>>(wconv, wfrag);
  premod_kernel<<<BB * 16 * 64 * 64 * 4 / 256, 256, 0, stream>>>(input, smod, xt);
  conv_mfma<<<BB * 4 * 16, 256, 0, stream>>>(xt, wfrag, demod, out);
}